// Round 14
// baseline (391.011 us; speedup 1.0000x reference)
//
#include <hip/hip_runtime.h>
#include <hip/hip_bf16.h>

// ActLayer: out[b,o] = sum_{i,f} norm(sin(w_f x[b,i] + p_f)) * beta[f,o] * lamb[i,o] + bias[o]
//
// Round-16: R15 (382us, verified) with per-block redundant VALU work moved to
// one-time prep kernels in d_ws (R15-proven pattern):
//   P1 betaR[f,o] = beta*r                        (128KB, verbatim R15)
//   P2 cvec[o]    = bias - (sum_f betaR*mean)*(sum_i lamb)   (2KB)
//   P3 lampk      = lambda in bf16, PRE-PACKED in the exact per-thread
//                   staging order (16KB per (i-tile, bn, chunk))   (512KB)
// Main kernel lambda staging becomes: 2 coalesced 16B loads + 2 b128 LDS
// writes per chunk (was 32 strided fp32 loads + 24 pack ops). c_sh prologue
// becomes a single cvec load (was 512 strided loads + trig per column).
// f-loop, A_sh dbuf sin-sharing cadence, direct v_sin, MFMA chains, epilogue:
// byte-identical to R15. Fallback template (no ws) = full R15 path.
//
// Geometry: BM=32 x BN=256, TB=512 (8 waves, 2m x 4n, 16x64/wave), grid 512,
// LDS 38.9KB, 2 blocks/CU, 4 waves/SIMD.

#define TB 512

typedef __attribute__((ext_vector_type(8))) short short8;
typedef __attribute__((ext_vector_type(4))) float floatx4;
typedef __attribute__((ext_vector_type(2))) unsigned int uintx2;
typedef __attribute__((ext_vector_type(4))) unsigned int uintx4;

// ws layout (floats): [0] betaR (32768) | [32768] cvec (512) | [33280] lampk (131072)
#define WS_CVEC  32768
#define WS_LAMPK 33280
#define WS_NEED  ((33280 + 131072) * sizeof(float))

// pack two fp32 -> two bf16 (round-half-up): two v_add + one v_perm_b32.
__device__ __forceinline__ unsigned pk_bf16(float a, float b) {
    union { float f; unsigned u; } ca, cb;
    ca.f = a; cb.f = b;
    unsigned ua = ca.u + 0x8000u;
    unsigned ub = cb.u + 0x8000u;
    return __builtin_amdgcn_perm(ub, ua, 0x07060302u);
}

// 4 bf16 sin values as 8B packed: sin(2*pi*(x*wfr + pfr)); direct v_sin
// (args bounded ~+-3.2 revolutions, inside HW internal-reduction domain).
__device__ __forceinline__ uintx2 sin_pack4(const float xv[4], float wfr, float pfr) {
    float s[4];
    #pragma unroll
    for (int j = 0; j < 4; ++j) {
        s[j] = __builtin_amdgcn_sinf(fmaf(xv[j], wfr, pfr));
    }
    uintx2 r;
    r.x = pk_bf16(s[0], s[1]);
    r.y = pk_bf16(s[2], s[3]);
    return r;
}

// ---- P1: betaR[f*O+n] = beta[f*O+n] * r_f ----
__global__ __launch_bounds__(256)
void betar_kernel(const float* __restrict__ freqs, const float* __restrict__ phases,
                  const float* __restrict__ beta, float* __restrict__ ws)
{
    int idx = blockIdx.x * 256 + threadIdx.x;   // 0..32767
    int f = idx >> 9;
    float wq = freqs[f], ph = phases[f];
    float e1 = expf(-0.5f * wq * wq);
    float mean = e1 * sinf(ph);
    float e2 = expf(-2.0f * wq * wq);
    float var = 0.5f - 0.5f * e2 * cosf(2.0f * ph) - mean * mean;
    float r = 1.0f / sqrtf(1e-3f + var);
    ws[idx] = beta[idx] * r;
}

// ---- P2: cvec[col] = bias - (sum_f betaR*mean_f) * (sum_i lamb[i][col]) ----
__global__ __launch_bounds__(256)
void cvec_kernel(const float* __restrict__ freqs, const float* __restrict__ phases,
                 const float* __restrict__ lamb, const float* __restrict__ bias,
                 float* __restrict__ ws)
{
    int col = blockIdx.x * 256 + threadIdx.x;   // 0..511
    float sb = 0.f;
    #pragma unroll 4
    for (int f = 0; f < 64; ++f) {
        float wq = freqs[f], ph = phases[f];
        float mean = expf(-0.5f * wq * wq) * sinf(ph);
        sb += ws[f * 512 + col] * mean;
    }
    float sl = 0.f;
    #pragma unroll 8
    for (int i = 0; i < 512; ++i) sl += lamb[(size_t)i * 512 + col];
    ws[WS_CVEC + col] = bias[col] - sb * sl;
}

// ---- P3: lampk = bf16(lamb) pre-packed in per-thread staging order.
// chunk ci = (it*2+bn)*2+c; thread t' (0..511): cL=t'&127, khL=t'>>7;
// 16 bf16 = lamb[it*64 + khL*16 + k][bn*256 + c*128 + cL], k=0..15, pair-packed.
__global__ __launch_bounds__(256)
void lampk_kernel(const float* __restrict__ lamb, float* __restrict__ ws)
{
    int id = blockIdx.x * 256 + threadIdx.x;    // 0..16383 (one 32B chunk each)
    int tp = id & 511;
    int c  = (id >> 9) & 1;
    int bn = (id >> 10) & 1;
    int it = id >> 11;
    int cL = tp & 127, khL = tp >> 7;
    const float* lp = lamb + (size_t)(it * 64 + khL * 16) * 512 + bn * 256 + c * 128 + cL;
    unsigned o[8];
    #pragma unroll
    for (int q = 0; q < 8; ++q) {
        float v0 = lp[(size_t)(2 * q) * 512];
        float v1 = lp[(size_t)(2 * q + 1) * 512];
        o[q] = pk_bf16(v0, v1);
    }
    uintx4* dst = (uintx4*)(ws + WS_LAMPK) + id * 2;
    uintx4 w0, w1;
    w0.x = o[0]; w0.y = o[1]; w0.z = o[2]; w0.w = o[3];
    w1.x = o[4]; w1.y = o[5]; w1.z = o[6]; w1.w = o[7];
    dst[0] = w0;
    dst[1] = w1;
}

template<bool PRE>
__global__ __launch_bounds__(TB, 4)
void actlayer_kernel(const float* __restrict__ x,
                     const float* __restrict__ freqs,
                     const float* __restrict__ phases,
                     const float* __restrict__ beta,
                     const float* __restrict__ lamb,
                     const float* __restrict__ bias,
                     const float* __restrict__ ws,   // betaR|cvec|lampk (PRE) or null
                     float* __restrict__ out)
{
    constexpr int I = 512, F = 64, O = 512;
    const int t  = threadIdx.x;
    const int bx = blockIdx.x;
    const int bn = bx & 1;            // 0..1
    const int bm = bx >> 1;           // 0..255
    const int n0 = bn * 256;
    const int m0 = bm * 32;

    __shared__ __align__(16) unsigned short A_sh[2][2][32][72]; // sin tiles, dbuf
    __shared__ __align__(16) unsigned short L_scr[128][72];     // lambda chunk
    __shared__ float wrev_sh[F], prev_sh[F], r_sh[F], m_sh[F];
    __shared__ float c_sh[256];

    // ---- prologue ----
    if (t < F) {
        float wq = freqs[t];
        float ph = phases[t];
        wrev_sh[t] = wq * 0.15915494309189535f;
        prev_sh[t] = ph * 0.15915494309189535f;
        if (!PRE) {
            float e1 = expf(-0.5f * wq * wq);
            float mean = e1 * sinf(ph);
            float e2 = expf(-2.0f * wq * wq);
            float var = 0.5f - 0.5f * e2 * cosf(2.0f * ph) - mean * mean;
            r_sh[t] = 1.0f / sqrtf(1e-3f + var);
            m_sh[t] = mean;
        }
    }
    if (PRE) {
        if (t < 256) c_sh[t] = ws[WS_CVEC + n0 + t];
    } else {
        __syncthreads();
        if (t < 256) {
            int col = n0 + t;
            float sb = 0.f;
            #pragma unroll 8
            for (int f = 0; f < F; ++f) sb += beta[f * O + col] * r_sh[f] * m_sh[f];
            float sl = 0.f;
            #pragma unroll 8
            for (int i = 0; i < I; ++i) sl += lamb[(size_t)i * O + col];
            c_sh[t] = bias[col] - sb * sl;
        }
    }

    // ---- wave geometry: 8 waves = 2 m-groups x 4 n-groups; tile 16 x 64 ----
    const int lane = t & 63;
    const int wid  = t >> 6;
    const int mg   = wid >> 2;        // 0..1
    const int ngw  = wid & 3;         // 0..3 (cols n0 + ngw*64 .. +63)
    const int l15  = lane & 15;
    const int quad = lane >> 4;
    // staging maps
    const int r0s = t >> 4;           // A staging row 0..31
    const int kqs = t & 15;           // A staging k-quad (k = kqs*4..+3)
    const int cL  = t & 127;          // L staging col within chunk
    const int khL = t >> 7;           // L staging k-quarter 0..3 (16 k each)

    floatx4 oacc[4];
    #pragma unroll
    for (int nt = 0; nt < 4; ++nt) oacc[nt] = (floatx4){0.f, 0.f, 0.f, 0.f};
    const floatx4 zero4 = (floatx4){0.f, 0.f, 0.f, 0.f};

    const float* bp = (PRE ? ws : beta) + n0 + ngw * 64 + l15;
    const uintx4* lampk4 = PRE ? ((const uintx4*)(ws + WS_LAMPK)) : nullptr;

    #pragma unroll 1
    for (int it = 0; it < 8; ++it) {
        const int i0 = it * 64;
        // ---- lambda chunk 0 (cols n0..n0+127) -> L_scr ----
        if (PRE) {
            const uintx4* lp4 = lampk4 + (size_t)(((it * 2 + bn) * 2 + 0) * 512 + t) * 2;
            uintx4 w0 = lp4[0], w1 = lp4[1];
            *(uintx4*)&L_scr[cL][khL * 16]     = w0;
            *(uintx4*)&L_scr[cL][khL * 16 + 8] = w1;
        } else {
            const float* lp = lamb + (size_t)(i0 + khL * 16) * O + n0 + cL;
            float v[16];
            #pragma unroll
            for (int k = 0; k < 16; ++k) v[k] = lp[(size_t)k * O];
            #pragma unroll
            for (int rr = 0; rr < 2; ++rr) {
                uintx4 w4;
                w4.x = pk_bf16(v[rr*8+0], v[rr*8+1]);
                w4.y = pk_bf16(v[rr*8+2], v[rr*8+3]);
                w4.z = pk_bf16(v[rr*8+4], v[rr*8+5]);
                w4.w = pk_bf16(v[rr*8+6], v[rr*8+7]);
                *(uintx4*)&L_scr[cL][khL * 16 + rr * 8] = w4;
            }
        }
        // x -> regs for sin staging: x[m0+r0s][i0 + kqs*4 .. +3]
        float xs[4];
        {
            float4 xv = *(const float4*)(x + (size_t)(m0 + r0s) * I + i0 + kqs * 4);
            xs[0] = xv.x; xs[1] = xv.y; xs[2] = xv.z; xs[3] = xv.w;
        }
        __syncthreads();   // chunk 0 visible
        short8 lf[2][4];
        if (ngw < 2) {
            #pragma unroll
            for (int kk = 0; kk < 2; ++kk)
                #pragma unroll
                for (int nt = 0; nt < 4; ++nt)
                    lf[kk][nt] = *(const short8*)&L_scr[ngw*64 + nt*16 + l15][kk*32 + quad*8];
        }
        __syncthreads();   // chunk-0 reads done
        // ---- lambda chunk 1 (cols n0+128..n0+255) -> L_scr ----
        if (PRE) {
            const uintx4* lp4 = lampk4 + (size_t)(((it * 2 + bn) * 2 + 1) * 512 + t) * 2;
            uintx4 w0 = lp4[0], w1 = lp4[1];
            *(uintx4*)&L_scr[cL][khL * 16]     = w0;
            *(uintx4*)&L_scr[cL][khL * 16 + 8] = w1;
        } else {
            const float* lp = lamb + (size_t)(i0 + khL * 16) * O + n0 + 128 + cL;
            float v[16];
            #pragma unroll
            for (int k = 0; k < 16; ++k) v[k] = lp[(size_t)k * O];
            #pragma unroll
            for (int rr = 0; rr < 2; ++rr) {
                uintx4 w4;
                w4.x = pk_bf16(v[rr*8+0], v[rr*8+1]);
                w4.y = pk_bf16(v[rr*8+2], v[rr*8+3]);
                w4.z = pk_bf16(v[rr*8+4], v[rr*8+5]);
                w4.w = pk_bf16(v[rr*8+6], v[rr*8+7]);
                *(uintx4*)&L_scr[cL][khL * 16 + rr * 8] = w4;
            }
        }
        // sins for f=0,1 -> A_sh[0] (both buffers idle at i-tile start)
        *(uintx2*)&A_sh[0][0][r0s][kqs * 4] = sin_pack4(xs, wrev_sh[0], prev_sh[0]);
        *(uintx2*)&A_sh[0][1][r0s][kqs * 4] = sin_pack4(xs, wrev_sh[1], prev_sh[1]);
        __syncthreads();   // chunk 1 + A_sh[0] visible
        if (ngw >= 2) {
            #pragma unroll
            for (int kk = 0; kk < 2; ++kk)
                #pragma unroll
                for (int nt = 0; nt < 4; ++nt)
                    lf[kk][nt] = *(const short8*)&L_scr[(ngw-2)*64 + nt*16 + l15][kk*32 + quad*8];
        }

        // betaR prefetch for f=0,1
        float bA[4], bB[4];
        #pragma unroll
        for (int nt = 0; nt < 4; ++nt) {
            bA[nt] = bp[0 * O + nt * 16];
            bB[nt] = bp[1 * O + nt * 16];
        }
        float rA = r_sh[0], rB = r_sh[1];

        // ---- f-loop: 2 f per iteration, dbuf A_sh, ONE barrier per pair ----
        int cur = 0;
        #pragma unroll 1
        for (int f = 0; f < F; f += 2) {
            const int arow = mg * 16 + l15;
            short8 afA0 = *(const short8*)&A_sh[cur][0][arow][quad * 8];
            short8 afA1 = *(const short8*)&A_sh[cur][0][arow][32 + quad * 8];
            short8 afB0 = *(const short8*)&A_sh[cur][1][arow][quad * 8];
            short8 afB1 = *(const short8*)&A_sh[cur][1][arow][32 + quad * 8];
            float brA[4], brB[4];
            #pragma unroll
            for (int q = 0; q < 4; ++q) {
                brA[q] = PRE ? bA[q] : bA[q] * rA;
                brB[q] = PRE ? bB[q] : bB[q] * rB;
            }
            const bool more = (f + 2 < F);
            if (more) {
                #pragma unroll
                for (int nt = 0; nt < 4; ++nt) {
                    bA[nt] = bp[(f + 2) * O + nt * 16];
                    bB[nt] = bp[(f + 3) * O + nt * 16];
                }
                if (!PRE) { rA = r_sh[f + 2]; rB = r_sh[f + 3]; }
                // sins for f+2 -> other buffer, dovetailed before MFMA chain A
                *(uintx2*)&A_sh[cur ^ 1][0][r0s][kqs * 4] =
                    sin_pack4(xs, wrev_sh[f + 2], prev_sh[f + 2]);
            }
            // MFMA chain A
            #pragma unroll
            for (int nt = 0; nt < 4; ++nt) {
                floatx4 s = __builtin_amdgcn_mfma_f32_16x16x32_bf16(
                    afA0, lf[0][nt], zero4, 0, 0, 0);
                s = __builtin_amdgcn_mfma_f32_16x16x32_bf16(
                    afA1, lf[1][nt], s, 0, 0, 0);
                oacc[nt] += brA[nt] * s;
            }
            if (more) {
                // sins for f+3, dovetailed before MFMA chain B
                *(uintx2*)&A_sh[cur ^ 1][1][r0s][kqs * 4] =
                    sin_pack4(xs, wrev_sh[f + 3], prev_sh[f + 3]);
            }
            // MFMA chain B
            #pragma unroll
            for (int nt = 0; nt < 4; ++nt) {
                floatx4 s = __builtin_amdgcn_mfma_f32_16x16x32_bf16(
                    afB0, lf[0][nt], zero4, 0, 0, 0);
                s = __builtin_amdgcn_mfma_f32_16x16x32_bf16(
                    afB1, lf[1][nt], s, 0, 0, 0);
                oacc[nt] += brB[nt] * s;
            }
            __syncthreads();
            cur ^= 1;
        }
    }

    // ---- epilogue: add per-column constant, store fp32 ----
    #pragma unroll
    for (int nt = 0; nt < 4; ++nt) {
        int cn = ngw * 64 + nt * 16 + l15;
        int gn = n0 + cn;
        float cv = c_sh[cn];
        int gm = m0 + mg * 16 + quad * 4;
        #pragma unroll
        for (int rg = 0; rg < 4; ++rg) {
            out[(size_t)(gm + rg) * O + gn] = oacc[nt][rg] + cv;
        }
    }
}

extern "C" void kernel_launch(void* const* d_in, const int* in_sizes, int n_in,
                              void* d_out, int out_size, void* d_ws, size_t ws_size,
                              hipStream_t stream) {
    const float* x      = (const float*)d_in[0];
    const float* freqs  = (const float*)d_in[1];
    const float* phases = (const float*)d_in[2];
    const float* beta   = (const float*)d_in[3];
    const float* lamb   = (const float*)d_in[4];
    const float* bias   = (const float*)d_in[5];
    float* out = (float*)d_out;

    dim3 grid(512);
    dim3 block(TB);
    if (d_ws != nullptr && ws_size >= WS_NEED) {
        float* ws = (float*)d_ws;
        hipLaunchKernelGGL(betar_kernel, dim3(128), dim3(256), 0, stream,
                           freqs, phases, beta, ws);
        hipLaunchKernelGGL(cvec_kernel, dim3(2), dim3(256), 0, stream,
                           freqs, phases, lamb, bias, ws);
        hipLaunchKernelGGL(lampk_kernel, dim3(64), dim3(256), 0, stream,
                           lamb, ws);
        hipLaunchKernelGGL(actlayer_kernel<true>, grid, block, 0, stream,
                           x, freqs, phases, beta, lamb, bias, ws, out);
    } else {
        hipLaunchKernelGGL(actlayer_kernel<false>, grid, block, 0, stream,
                           x, freqs, phases, beta, lamb, bias, nullptr, out);
    }
}

// Round 15
// 390.480 us; speedup vs baseline: 1.0014x; 1.0014x over previous
//
#include <hip/hip_runtime.h>
#include <hip/hip_bf16.h>

// ActLayer: out[b,o] = sum_{i,f} norm(sin(w_f x[b,i] + p_f)) * beta[f,o] * lamb[i,o] + bias[o]
//
// Round-17: BN=512 + fragment-direct lambda (kills the R11 blocker) + fused prep.
//   Block = 16 rows x 512 cols, TB=512 (8 waves, each 16x64), grid 512.
//   Sin work halves vs R16 (no column duplication at all: B*I*F total);
//   each thread does ONE sin_pack4 per f-pair (f-half split by t>>8).
//   Lambda is NEVER staged in LDS: prep kernel writes bf16 lambda in exact
//   per-(thread,fragment) order; main loads lf[kk][nt] with 8 coalesced 16B
//   reads per i-tile from ws (512KB, L2-resident).
//   Prep fused into ONE kernel (betaR | cvec | lam-frag), launches 4 -> 2.
// Proven pieces verbatim: A_sh dbuf + 1-barrier-per-f-pair cadence (R10/R16),
// direct v_sin (R15), v_perm bf16 pack (R8), betaR register prefetch (R13),
// MFMA chains + C/D epilogue mapping (R3 lineage).
// LDS ~12KB, 2 blocks/CU, 4 waves/SIMD, VGPR ~100.

#define TB 512

typedef __attribute__((ext_vector_type(8))) short short8;
typedef __attribute__((ext_vector_type(4))) float floatx4;
typedef __attribute__((ext_vector_type(2))) unsigned int uintx2;
typedef __attribute__((ext_vector_type(4))) unsigned int uintx4;

// ws layout (floats): [0] betaR (32768) | [32768] cvec (512) | [33280] lamf (131072)
#define WS_CVEC  32768
#define WS_LAMF  33280
#define WS_NEED  ((33280 + 131072) * sizeof(float))

// pack two fp32 -> two bf16 (round-half-up): two v_add + one v_perm_b32.
__device__ __forceinline__ unsigned pk_bf16(float a, float b) {
    union { float f; unsigned u; } ca, cb;
    ca.f = a; cb.f = b;
    unsigned ua = ca.u + 0x8000u;
    unsigned ub = cb.u + 0x8000u;
    return __builtin_amdgcn_perm(ub, ua, 0x07060302u);
}

// 4 bf16 sin values as 8B packed: sin(2*pi*(x*wfr + pfr)); direct v_sin
// (args bounded ~+-3.2 revolutions, inside HW internal-reduction domain).
__device__ __forceinline__ uintx2 sin_pack4(const float xv[4], float wfr, float pfr) {
    float s[4];
    #pragma unroll
    for (int j = 0; j < 4; ++j) {
        s[j] = __builtin_amdgcn_sinf(fmaf(xv[j], wfr, pfr));
    }
    uintx2 r;
    r.x = pk_bf16(s[0], s[1]);
    r.y = pk_bf16(s[2], s[3]);
    return r;
}

// ---- fused prep: blocks 0-127 betaR | 128-129 cvec | 130-257 lambda frags ----
__global__ __launch_bounds__(256)
void prep_kernel(const float* __restrict__ freqs, const float* __restrict__ phases,
                 const float* __restrict__ beta, const float* __restrict__ lamb,
                 const float* __restrict__ bias, float* __restrict__ ws)
{
    const int bid = blockIdx.x, tid = threadIdx.x;
    if (bid < 128) {
        // betaR[f*512+n] = beta * r_f
        int idx = bid * 256 + tid;            // 0..32767
        int f = idx >> 9;
        float wq = freqs[f], ph = phases[f];
        float mean = expf(-0.5f * wq * wq) * sinf(ph);
        float var = 0.5f - 0.5f * expf(-2.0f * wq * wq) * cosf(2.0f * ph) - mean * mean;
        ws[idx] = beta[idx] * (1.0f / sqrtf(1e-3f + var));
    } else if (bid < 130) {
        // cvec[col] = bias - (sum_f betaR*mean_f) * (sum_i lamb[i][col])
        int col = (bid - 128) * 256 + tid;    // 0..511
        float sb = 0.f;
        for (int f = 0; f < 64; ++f) {
            float wq = freqs[f], ph = phases[f];
            float mean = expf(-0.5f * wq * wq) * sinf(ph);
            float var = 0.5f - 0.5f * expf(-2.0f * wq * wq) * cosf(2.0f * ph) - mean * mean;
            float r = 1.0f / sqrtf(1e-3f + var);
            sb += beta[f * 512 + col] * r * mean;
        }
        float sl = 0.f;
        #pragma unroll 8
        for (int i = 0; i < 512; ++i) sl += lamb[(size_t)i * 512 + col];
        ws[WS_CVEC + col] = bias[col] - sb * sl;
    } else {
        // lamf[g] (16B): fragment (it, frag, thread) of bf16 lambda.
        // g = (it*8 + frag)*512 + t ; frag = kk*4+nt ;
        // lf[j] = bf16(lamb[it*64 + kk*32 + quad*8 + j][wid*64 + nt*16 + l15])
        int g = (bid - 130) * 256 + tid;      // 0..32767
        int it = g >> 12;
        int frag = (g >> 9) & 7;
        int tt = g & 511;
        int kk = frag >> 2, nt = frag & 3;
        int wid = tt >> 6, lane = tt & 63;
        int l15 = lane & 15, quad = lane >> 4;
        int col = wid * 64 + nt * 16 + l15;
        const float* lp = lamb + (size_t)(it * 64 + kk * 32 + quad * 8) * 512 + col;
        uintx4 w4;
        w4.x = pk_bf16(lp[0],            lp[(size_t)1 * 512]);
        w4.y = pk_bf16(lp[(size_t)2*512], lp[(size_t)3 * 512]);
        w4.z = pk_bf16(lp[(size_t)4*512], lp[(size_t)5 * 512]);
        w4.w = pk_bf16(lp[(size_t)6*512], lp[(size_t)7 * 512]);
        ((uintx4*)(ws + WS_LAMF))[g] = w4;
    }
}

template<bool PRE>
__global__ __launch_bounds__(TB, 4)
void actlayer_kernel(const float* __restrict__ x,
                     const float* __restrict__ freqs,
                     const float* __restrict__ phases,
                     const float* __restrict__ beta,
                     const float* __restrict__ lamb,
                     const float* __restrict__ bias,
                     const float* __restrict__ ws,
                     float* __restrict__ out)
{
    constexpr int I = 512, F = 64, O = 512;
    const int t  = threadIdx.x;
    const int m0 = blockIdx.x * 16;

    __shared__ __align__(16) unsigned short A_sh[2][2][16][72]; // sin tiles, dbuf, 9216B
    __shared__ float wrev_sh[F], prev_sh[F], r_sh[F], m_sh[F];
    __shared__ float c_sh[512];

    // ---- prologue ----
    if (t < F) {
        float wq = freqs[t];
        float ph = phases[t];
        wrev_sh[t] = wq * 0.15915494309189535f;
        prev_sh[t] = ph * 0.15915494309189535f;
        if (!PRE) {
            float mean = expf(-0.5f * wq * wq) * sinf(ph);
            float var = 0.5f - 0.5f * expf(-2.0f * wq * wq) * cosf(2.0f * ph) - mean * mean;
            r_sh[t] = 1.0f / sqrtf(1e-3f + var);
            m_sh[t] = mean;
        }
    }
    if (PRE) {
        c_sh[t] = ws[WS_CVEC + t];
    } else {
        __syncthreads();
        int col = t;
        float sb = 0.f;
        #pragma unroll 8
        for (int f = 0; f < F; ++f) sb += beta[f * O + col] * r_sh[f] * m_sh[f];
        float sl = 0.f;
        #pragma unroll 8
        for (int i = 0; i < I; ++i) sl += lamb[(size_t)i * O + col];
        c_sh[t] = bias[col] - sb * sl;
    }
    __syncthreads();   // wrev/prev (+c_sh) visible before first staging

    // ---- geometry: 8 waves, wave w owns rows [m0,m0+16) x cols [64w,64w+64) ----
    const int lane = t & 63;
    const int wid  = t >> 6;
    const int l15  = lane & 15;
    const int quad = lane >> 4;
    // sin staging map: f-half fh, row rs, k-quad kq
    const int fh = t >> 8;            // 0..1
    const int rs = (t >> 4) & 15;     // 0..15
    const int kq = t & 15;            // k = kq*4 .. +3

    floatx4 oacc[4];
    #pragma unroll
    for (int nt = 0; nt < 4; ++nt) oacc[nt] = (floatx4){0.f, 0.f, 0.f, 0.f};
    const floatx4 zero4 = (floatx4){0.f, 0.f, 0.f, 0.f};

    const float* bp = (PRE ? ws : beta) + wid * 64 + l15;
    const uintx4* lamf = (const uintx4*)(ws + WS_LAMF);

    #pragma unroll 1
    for (int it = 0; it < 8; ++it) {
        const int i0 = it * 64;
        // x -> regs for sin staging: x[m0+rs][i0 + kq*4 .. +3]
        float xs[4];
        {
            float4 xv = *(const float4*)(x + (size_t)(m0 + rs) * I + i0 + kq * 4);
            xs[0] = xv.x; xs[1] = xv.y; xs[2] = xv.z; xs[3] = xv.w;
        }
        // lambda fragments: direct coalesced loads (PRE) or strided+pack fallback
        short8 lf[2][4];
        if (PRE) {
            #pragma unroll
            for (int kk = 0; kk < 2; ++kk)
                #pragma unroll
                for (int nt = 0; nt < 4; ++nt) {
                    union { uintx4 u; short8 h; } cv;
                    cv.u = lamf[(size_t)((it * 8 + kk * 4 + nt) * 512) + t];
                    lf[kk][nt] = cv.h;
                }
        } else {
            #pragma unroll
            for (int kk = 0; kk < 2; ++kk)
                #pragma unroll
                for (int nt = 0; nt < 4; ++nt) {
                    const float* lp = lamb + (size_t)(i0 + kk * 32 + quad * 8) * O
                                    + wid * 64 + nt * 16 + l15;
                    union { uintx4 u; short8 h; } cv;
                    cv.u.x = pk_bf16(lp[0],              lp[(size_t)1 * O]);
                    cv.u.y = pk_bf16(lp[(size_t)2 * O], lp[(size_t)3 * O]);
                    cv.u.z = pk_bf16(lp[(size_t)4 * O], lp[(size_t)5 * O]);
                    cv.u.w = pk_bf16(lp[(size_t)6 * O], lp[(size_t)7 * O]);
                    lf[kk][nt] = cv.h;
                }
        }
        // stage sins for f=0,1 into buf 0: ONE sin_pack4 per thread (f-half fh)
        *(uintx2*)&A_sh[0][fh][rs][kq * 4] = sin_pack4(xs, wrev_sh[fh], prev_sh[fh]);
        __syncthreads();   // A_sh[0] ready

        // betaR prefetch for f=0,1
        float bA[4], bB[4];
        #pragma unroll
        for (int nt = 0; nt < 4; ++nt) {
            bA[nt] = bp[0 * O + nt * 16];
            bB[nt] = bp[1 * O + nt * 16];
        }
        float rA = r_sh[0], rB = r_sh[1];

        // ---- f-loop: 2 f per iteration, dbuf A_sh, ONE barrier per pair ----
        int cur = 0;
        #pragma unroll 1
        for (int f = 0; f < F; f += 2) {
            short8 afA0 = *(const short8*)&A_sh[cur][0][l15][quad * 8];
            short8 afA1 = *(const short8*)&A_sh[cur][0][l15][32 + quad * 8];
            short8 afB0 = *(const short8*)&A_sh[cur][1][l15][quad * 8];
            short8 afB1 = *(const short8*)&A_sh[cur][1][l15][32 + quad * 8];
            float brA[4], brB[4];
            #pragma unroll
            for (int q = 0; q < 4; ++q) {
                brA[q] = PRE ? bA[q] : bA[q] * rA;
                brB[q] = PRE ? bB[q] : bB[q] * rB;
            }
            const bool more = (f + 2 < F);
            if (more) {
                #pragma unroll
                for (int nt = 0; nt < 4; ++nt) {
                    bA[nt] = bp[(f + 2) * O + nt * 16];
                    bB[nt] = bp[(f + 3) * O + nt * 16];
                }
                if (!PRE) { rA = r_sh[f + 2]; rB = r_sh[f + 3]; }
                // sins for f+2 (threads fh=0) / f+3 (fh=1) -> other buffer
                *(uintx2*)&A_sh[cur ^ 1][fh][rs][kq * 4] =
                    sin_pack4(xs, wrev_sh[f + 2 + fh], prev_sh[f + 2 + fh]);
            }
            // MFMA chain A
            #pragma unroll
            for (int nt = 0; nt < 4; ++nt) {
                floatx4 s = __builtin_amdgcn_mfma_f32_16x16x32_bf16(
                    afA0, lf[0][nt], zero4, 0, 0, 0);
                s = __builtin_amdgcn_mfma_f32_16x16x32_bf16(
                    afA1, lf[1][nt], s, 0, 0, 0);
                oacc[nt] += brA[nt] * s;
            }
            // MFMA chain B
            #pragma unroll
            for (int nt = 0; nt < 4; ++nt) {
                floatx4 s = __builtin_amdgcn_mfma_f32_16x16x32_bf16(
                    afB0, lf[0][nt], zero4, 0, 0, 0);
                s = __builtin_amdgcn_mfma_f32_16x16x32_bf16(
                    afB1, lf[1][nt], s, 0, 0, 0);
                oacc[nt] += brB[nt] * s;
            }
            __syncthreads();
            cur ^= 1;
        }
    }

    // ---- epilogue: add per-column constant, store fp32 ----
    #pragma unroll
    for (int nt = 0; nt < 4; ++nt) {
        int gn = wid * 64 + nt * 16 + l15;
        float cv = c_sh[gn];
        int gm = m0 + quad * 4;
        #pragma unroll
        for (int rg = 0; rg < 4; ++rg) {
            out[(size_t)(gm + rg) * O + gn] = oacc[nt][rg] + cv;
        }
    }
}

extern "C" void kernel_launch(void* const* d_in, const int* in_sizes, int n_in,
                              void* d_out, int out_size, void* d_ws, size_t ws_size,
                              hipStream_t stream) {
    const float* x      = (const float*)d_in[0];
    const float* freqs  = (const float*)d_in[1];
    const float* phases = (const float*)d_in[2];
    const float* beta   = (const float*)d_in[3];
    const float* lamb   = (const float*)d_in[4];
    const float* bias   = (const float*)d_in[5];
    float* out = (float*)d_out;

    dim3 grid(512);    // 8192/16 m-blocks; BN=512 covers all cols
    dim3 block(TB);
    if (d_ws != nullptr && ws_size >= WS_NEED) {
        float* ws = (float*)d_ws;
        hipLaunchKernelGGL(prep_kernel, dim3(258), dim3(256), 0, stream,
                           freqs, phases, beta, lamb, bias, ws);
        hipLaunchKernelGGL(actlayer_kernel<true>, grid, block, 0, stream,
                           x, freqs, phases, beta, lamb, bias, ws, out);
    } else {
        hipLaunchKernelGGL(actlayer_kernel<false>, grid, block, 0, stream,
                           x, freqs, phases, beta, lamb, bias, nullptr, out);
    }
}